// Round 14
// baseline (4785.738 us; speedup 1.0000x reference)
//
#include <hip/hip_runtime.h>

typedef unsigned short u16;
typedef unsigned int   u32;
typedef __bf16 bf16x8 __attribute__((ext_vector_type(8)));
typedef float  f32x4  __attribute__((ext_vector_type(4)));

#define DEVI __device__ __forceinline__

DEVI u16 f2bf(float f){
  u32 u = __builtin_bit_cast(u32, f);
  u32 r = (u + 0x7fffu + ((u >> 16) & 1u)) >> 16;   // RNE
  return (u16)r;
}
DEVI float bf2f(u16 u){
  u32 x = ((u32)u) << 16;
  return __builtin_bit_cast(float, x);
}

DEVI void gload16(const void* g, void* lds){
  __builtin_amdgcn_global_load_lds(
      (const __attribute__((address_space(1))) void*)g,
      (__attribute__((address_space(3))) void*)lds, 16, 0, 0);
}

DEVI f32x4 MFMA(bf16x8 a, bf16x8 b, f32x4 c){
  return __builtin_amdgcn_mfma_f32_16x16x32_bf16(a, b, c, 0, 0, 0);
}

#define BAR() do { asm volatile("s_barrier" ::: "memory"); \
                   __builtin_amdgcn_sched_barrier(0); } while(0)

// ---------------- mask dtype probe: 1 => uint8 bytes, 0 => int32 ----------------
__global__ void k_maskprobe(const unsigned char* __restrict__ m, int* __restrict__ flag){
  __shared__ int s;
  if (threadIdx.x == 0) s = 0;
  __syncthreads();
  int acc = 0;
  for (int i = threadIdx.x; i < 65536; i += 256)
    if ((i & 3) != 0 && m[i] != 0) acc++;
  atomicAdd(&s, acc);
  __syncthreads();
  if (threadIdx.x == 0) *flag = (s > 0) ? 1 : 0;
}

// ---------------- pack attn_mask to bitmask [B*S][16 words] ----------------
__global__ void k_maskbits(const void* __restrict__ mask, const int* __restrict__ flag,
                           u32* __restrict__ mb){
  int row  = blockIdx.x * 4 + (threadIdx.x >> 6);   // b*512+q
  int lane = threadIdx.x & 63;
  bool bytes = (*flag != 0);
  for (int c0 = 0; c0 < 512; c0 += 64){
    int v;
    if (bytes) v = ((const unsigned char*)mask)[(size_t)row * 512 + c0 + lane];
    else       v = ((const int*)mask)[(size_t)row * 512 + c0 + lane];
    unsigned long long bits = __ballot(v != 0);
    if (lane == 0){
      mb[(size_t)row * 16 + (c0 >> 5)]     = (u32)(bits & 0xffffffffull);
      mb[(size_t)row * 16 + (c0 >> 5) + 1] = (u32)(bits >> 32);
    }
  }
}

// ---------------- fused embed + node-average + LN0 -> bf16 hb ----------------
__global__ void k_embln(const int* __restrict__ ids, const int* __restrict__ pos,
                        const u32* __restrict__ mb, const float* __restrict__ wemb,
                        const float* __restrict__ pemb, const float* __restrict__ g,
                        const float* __restrict__ be, u16* __restrict__ hb){
  __shared__ float s1[4], s2[4];
  int row = blockIdx.x, t = threadIdx.x;
  int p = pos[row];
  float x0, x1, x2;
  if (p == 0){
    int b = row >> 9;
    const u32* mrow = mb + (size_t)row * 16;
    const int* pb = pos + ((size_t)b << 9);
    const int* ib = ids + ((size_t)b << 9);
    float a0 = 0.f, a1 = 0.f, a2 = 0.f, cnt = 0.f;
    #pragma unroll 8
    for (int k = 0; k < 512; k++){
      float w = (pb[k] >= 2 && ((mrow[k >> 5] >> (k & 31)) & 1)) ? 1.f : 0.f;
      const float* src = wemb + (size_t)ib[k] * 768;
      a0 += w * src[t]; a1 += w * src[t+256]; a2 += w * src[t+512];
      cnt += w;
    }
    float inv = 1.f / (cnt + 1e-10f);
    x0 = a0 * inv; x1 = a1 * inv; x2 = a2 * inv;
  } else {
    const float* src = wemb + (size_t)ids[row] * 768;
    x0 = src[t]; x1 = src[t+256]; x2 = src[t+512];
  }
  const float* pr = pemb + (size_t)p * 768;
  x0 += pr[t]; x1 += pr[t+256]; x2 += pr[t+512];
  float s = x0 + x1 + x2, q = x0*x0 + x1*x1 + x2*x2;
  for (int o = 32; o; o >>= 1){ s += __shfl_down(s, o, 64); q += __shfl_down(q, o, 64); }
  int wv = t >> 6, ln = t & 63;
  if (!ln){ s1[wv] = s; s2[wv] = q; }
  __syncthreads();
  s = s1[0]+s1[1]+s1[2]+s1[3]; q = s2[0]+s2[1]+s2[2]+s2[3];
  float mu = s * (1.f/768.f);
  float rs = rsqrtf(q * (1.f/768.f) - mu*mu + 1e-5f);
  u16* hbr = hb + (size_t)row * 768;
  hbr[t]     = f2bf((x0-mu)*rs*g[t]     + be[t]);
  hbr[t+256] = f2bf((x1-mu)*rs*g[t+256] + be[t+256]);
  hbr[t+512] = f2bf((x2-mu)*rs*g[t+512] + be[t+512]);
}

// lnres: hb (bf16, in-place) + C (bf16) -> LN -> hb
__global__ void k_lnres(const u16* __restrict__ C, const float* __restrict__ g,
                        const float* __restrict__ be, u16* __restrict__ hb){
  __shared__ float s1[4], s2[4];
  int row = blockIdx.x, t = threadIdx.x;
  u16* hr = hb + (size_t)row * 768;
  const u16* cr = C + (size_t)row * 768;
  float x0 = bf2f(hr[t])     + bf2f(cr[t]);
  float x1 = bf2f(hr[t+256]) + bf2f(cr[t+256]);
  float x2 = bf2f(hr[t+512]) + bf2f(cr[t+512]);
  float s = x0 + x1 + x2, q = x0*x0 + x1*x1 + x2*x2;
  for (int o = 32; o; o >>= 1){ s += __shfl_down(s, o, 64); q += __shfl_down(q, o, 64); }
  int wv = t >> 6, ln = t & 63;
  if (!ln){ s1[wv] = s; s2[wv] = q; }
  __syncthreads();
  s = s1[0]+s1[1]+s1[2]+s1[3]; q = s2[0]+s2[1]+s2[2]+s2[3];
  float mu = s * (1.f/768.f);
  float rs = rsqrtf(q * (1.f/768.f) - mu*mu + 1e-5f);
  hr[t]     = f2bf((x0-mu)*rs*g[t]     + be[t]);
  hr[t+256] = f2bf((x1-mu)*rs*g[t+256] + be[t+256]);
  hr[t+512] = f2bf((x2-mu)*rs*g[t+512] + be[t+512]);
}

// ---------------- weight transpose+cast: src[K][N] f32 -> dst[N][K] bf16 ----------------
__global__ void k_transpose(const float* __restrict__ src, u16* __restrict__ dst,
                            int K, int N){
  __shared__ float tile[32][33];
  int k0 = blockIdx.x * 32, n0 = blockIdx.y * 32;
  int tx = threadIdx.x & 31, ty = threadIdx.x >> 5;   // ty 0..7
  #pragma unroll
  for (int i = 0; i < 32; i += 8)
    tile[ty + i][tx] = src[(size_t)(k0 + ty + i) * N + n0 + tx];
  __syncthreads();
  #pragma unroll
  for (int i = 0; i < 32; i += 8)
    dst[(size_t)(n0 + ty + i) * K + k0 + tx] = f2bf(tile[tx][ty + i]);
}

// ========== 128x256 BK=32 GEMM: A LDS-staged (dist-2), B direct-from-global regs ==========
// LDS main loop: A only, 3 x [128][32] bf16 (24 KB of the 72 KB block; rest for epilogue).
// B fragments double-buffered in registers (X/Y), loaded t+1 ahead. NT % 6 == 0 required
// (all call sites: K=768 -> NT=24, K=3072 -> NT=96). One barrier per K-tile.
// vmcnt ledger per iter (issue order: stageA(t+2)[1], B(t+1)[4]):
//   entering: [A(t+1), B(t)x4]; after issue: 10 outstanding; vmcnt(5) retires A(t+1)+B(t).
// EPI 0: bf16+bias; 1: f32+bias; 2: bf16+bias+GELU;
// EPI 3: qkv -> head-packed q/k (n0<1536) or direct transposed V write to vt (n0>=1536).

DEVI void stageA32(const u16* __restrict__ src, int K, u16* lds, int tid){
  int r = tid >> 2, c = tid & 3;
  int sc = c ^ ((r >> 1) & 3);
  gload16(src + (size_t)r*K + sc*8, lds + (size_t)tid*8);
}

template<int EPI>
__global__ __launch_bounds__(512, 4)
void k_gemm3(const u16* __restrict__ A, const u16* __restrict__ BT,
             const float* __restrict__ bias, void* __restrict__ out,
             void* __restrict__ out2, int M, int N, int K){
  __shared__ __align__(16) u16 sm[36864];   // 72 KiB (loop uses first 24 KB)
  const int tid = threadIdx.x;
  const int w = tid >> 6, lane = tid & 63;
  const int wm = w >> 2, wn = w & 3;
  const int cr = lane & 15, cg = lane >> 4;

  // bijective XCD-chunked remap (m204)
  const int nbn = gridDim.x;
  const int nwg = nbn * gridDim.y;
  const int d   = blockIdx.y * nbn + blockIdx.x;
  const int xcd = d & 7, qq = nwg >> 3, rr = nwg & 7;
  const int logical = (xcd < rr ? xcd*(qq+1) : rr*(qq+1) + (xcd-rr)*qq) + (d >> 3);
  const int m0 = (logical / nbn) * 128;
  const int n0 = (logical % nbn) * 256;

  const int NT = K >> 5;
  const u16* Abase = A + (size_t)m0 * K;
  const int rowA = wm*64 + cr;

  // per-lane B fragment pointers (rows n0+wn*64+n*16+cr, k-chunk cg*8)
  const u16* Bp0 = BT + (size_t)(n0 + wn*64 + cr) * K + cg*8;
  const u16* Bp1 = Bp0 + (size_t)16*K;
  const u16* Bp2 = Bp0 + (size_t)32*K;
  const u16* Bp3 = Bp0 + (size_t)48*K;

  f32x4 acc[4][4] = {};
  bf16x8 afr[4], bX[4], bY[4];

  // prologue: A(0)->buf0, A(1)->buf1, B(0)->bX
  stageA32(Abase,      K, sm,        tid);
  stageA32(Abase + 32, K, sm + 4096, tid);
  bX[0] = *(const bf16x8*)Bp0;
  bX[1] = *(const bf16x8*)Bp1;
  bX[2] = *(const bf16x8*)Bp2;
  bX[3] = *(const bf16x8*)Bp3;
  asm volatile("s_waitcnt vmcnt(5)" ::: "memory");   // retire A(0)
  __builtin_amdgcn_sched_barrier(0);
  BAR();

#define GITER(BC, BN, tt, ABCUR, ABST) { \
    _Pragma("unroll") \
    for (int i = 0; i < 4; i++){ \
      int r = rowA + i*16; \
      afr[i] = *(const bf16x8*)&sm[(ABCUR) + r*32 + ((cg ^ ((r >> 1) & 3)) << 3)]; \
    } \
    if ((tt) + 2 < NT) stageA32(Abase + (size_t)((tt)+2)*32, K, sm + (ABST), tid); \
    if ((tt) + 1 < NT){ \
      BN[0] = *(const bf16x8*)(Bp0 + ((tt)+1)*32); \
      BN[1] = *(const bf16x8*)(Bp1 + ((tt)+1)*32); \
      BN[2] = *(const bf16x8*)(Bp2 + ((tt)+1)*32); \
      BN[3] = *(const bf16x8*)(Bp3 + ((tt)+1)*32); \
    } \
    if ((tt) + 2 < NT)      { asm volatile("s_waitcnt vmcnt(5)" ::: "memory"); } \
    else if ((tt) + 1 < NT) { asm volatile("s_waitcnt vmcnt(4)" ::: "memory"); } \
    else                    { asm volatile("s_waitcnt vmcnt(0)" ::: "memory"); } \
    __builtin_amdgcn_sched_barrier(0); \
    __builtin_amdgcn_s_setprio(1); \
    _Pragma("unroll") \
    for (int i = 0; i < 4; i++) \
      _Pragma("unroll") \
      for (int n = 0; n < 4; n++) \
        acc[i][n] = MFMA(afr[i], BC[n], acc[i][n]); \
    __builtin_amdgcn_s_setprio(0); \
    BAR(); \
  }

  for (int t = 0; t < NT; t += 6){
    GITER(bX, bY, t+0, 0,    8192);
    GITER(bY, bX, t+1, 4096, 0);
    GITER(bX, bY, t+2, 8192, 4096);
    GITER(bY, bX, t+3, 0,    8192);
    GITER(bX, bY, t+4, 4096, 0);
    GITER(bY, bX, t+5, 8192, 4096);
  }
#undef GITER

  // ---- epilogue
  if (EPI == 1){
    #pragma unroll
    for (int n = 0; n < 4; n++){
      int col = n0 + wn*64 + n*16 + cr;
      float bv = bias[col];
      #pragma unroll
      for (int i = 0; i < 4; i++){
        #pragma unroll
        for (int j = 0; j < 4; j++){
          int row = m0 + wm*64 + i*16 + cg*4 + j;
          ((float*)out)[(size_t)row * N + col] = acc[i][n][j] + bv;
        }
      }
    }
  } else {
    const bool vblk = (EPI == 3) && (n0 >= 1536);
    const int LDC = vblk ? 266 : 264;
    #pragma unroll
    for (int n = 0; n < 4; n++){
      int coll = wn*64 + n*16 + cr;
      float bv = bias[n0 + coll];
      #pragma unroll
      for (int i = 0; i < 4; i++){
        #pragma unroll
        for (int j = 0; j < 4; j++){
          int rowl = wm*64 + i*16 + cg*4 + j;
          float v = acc[i][n][j] + bv;
          if (EPI == 2) v = 0.5f * v * (1.f + erff(v * 0.70710678118654752f));
          sm[rowl*LDC + coll] = f2bf(v);
        }
      }
    }
    BAR();
    if (EPI == 3){
      int b = m0 >> 9, s0 = m0 & 511;
      if (vblk){
        // direct transposed V write: vt[b*12+hd][d][s0..s0+127]
        int hd0 = (n0 - 1536) >> 6;
        int dl = lane >> 2, sc4 = lane & 3;
        #pragma unroll
        for (int it = 0; it < 8; it++){
          int gidx = it*8 + w;                 // 0..63
          int hh2 = gidx >> 4, dhi = (gidx >> 2) & 3, shi = gidx & 3;
          int dd2 = dhi*16 + dl;
          int schunk = shi*4 + sc4;
          u16 tmp[8];
          #pragma unroll
          for (int k = 0; k < 8; k++)
            tmp[k] = sm[(schunk*8 + k)*266 + hh2*64 + dd2];
          *(uint4*)((u16*)out2 + (((size_t)(b*12 + hd0 + hh2)*64 + dd2) << 9)
                    + s0 + schunk*8) = *(uint4*)tmp;
        }
      } else {
        // head-packed q/k scatter: 16B chunks, 128B contiguous per (s,head)
        #pragma unroll
        for (int it = 0; it < 8; it++){
          int idx = it*512 + tid;            // (s:128)(h:4)(c:8)
          int c = idx & 7, hh2 = (idx >> 3) & 3, s = idx >> 5;
          uint4 v4 = *(const uint4*)&sm[s*264 + hh2*64 + c*8];
          int col0 = n0 + hh2*64;
          int sec = (col0 >= 768) ? 1 : 0;
          int hd  = (col0 - sec*768) >> 6;
          *(uint4*)((u16*)out + (size_t)sec*25165824 +
                    (((size_t)(b*12 + hd)*512 + (m0 & 511) + s) << 6) + c*8) = v4;
        }
      }
    } else {
      #pragma unroll
      for (int it = 0; it < 8; it++){
        int idx = it*512 + tid;            // (r:128)(c8:32)
        int r = idx >> 5, c8 = idx & 31;
        uint4 v4 = *(const uint4*)&sm[r*264 + c8*8];
        *(uint4*)((u16*)out + (size_t)(m0 + r)*N + n0 + c8*8) = v4;
      }
    }
  }
}

// ---------------- attention v3: flash/online, swapped QK^T, LDS-staged K & V^T ----------
DEVI void stage64(const u16* __restrict__ src, int stride, u16* lds, int w, int lane){
  #pragma unroll
  for (int j = 0; j < 2; j++){
    int p  = j*256 + w*64 + lane;        // piece 0..511 (16B each)
    int r  = p >> 3;                     // row 0..63
    int c8 = (p & 7) ^ (r & 7);          // inverse-swizzled source chunk
    gload16(src + (size_t)r*stride + c8*8, lds + (size_t)p*8);
  }
}

__global__ __launch_bounds__(256, 4)
void k_attn3(const u16* __restrict__ qp, const u16* __restrict__ kp,
             const u16* __restrict__ vt, const u32* __restrict__ mb,
             u16* __restrict__ ctx){
  __shared__ __align__(16) u16 Ks[8192];   // 2 x [64][64]
  __shared__ __align__(16) u16 Vs[8192];   // 2 x [64 d][64 kv]
  const int tid = threadIdx.x, wv = tid >> 6, lane = tid & 63;
  const int cr = lane & 15, cg = lane >> 4;
  const int cg4 = cg * 4;
  const int r7 = cr & 7;

  const int dd = blockIdx.x + (blockIdx.y << 3);
  const int logical = (dd & 7) * 768 + (dd >> 3);
  const int bh = logical >> 3;
  const int qblk = logical & 7;
  const int b = bh / 12, hh = bh % 12;
  const int qw = qblk * 64 + wv * 16;
  const int qrow = qw + cr;
  const size_t base = (size_t)bh * 512 * 64;
  const u16* vtb = vt + (size_t)bh * 64 * 512;

  const int slot0 = ((cg    ) ^ r7) << 3;
  const int slot1 = ((4 + cg) ^ r7) << 3;

  bf16x8 qB[2];
  #pragma unroll
  for (int ks = 0; ks < 2; ks++)
    qB[ks] = *(const bf16x8*)&qp[base + (size_t)qrow * 64 + ks*32 + cg*8];

  u32 mw[16];
  {
    const u32* mrow = mb + ((size_t)b * 512 + qrow) * 16;
    #pragma unroll
    for (int i = 0; i < 4; i++){
      uint4 v4 = *(const uint4*)&mrow[i*4];
      mw[i*4+0] = v4.x; mw[i*4+1] = v4.y; mw[i*4+2] = v4.z; mw[i*4+3] = v4.w;
    }
  }

  stage64(kp + base, 64, Ks, wv, lane);
  stage64(vtb,      512, Vs, wv, lane);
  asm volatile("s_waitcnt vmcnt(0)" ::: "memory");
  __builtin_amdgcn_sched_barrier(0);
  BAR();

  float m = -3e38f, vs = 0.f;
  f32x4 oacc[4] = {};

  for (int s = 0; s < 8; ++s){
    const int buf = (s & 1) << 12;
    const int nbf = ((s + 1) & 1) << 12;

    if (s + 1 < 8){
      stage64(kp + base + (size_t)(s+1)*4096, 64, Ks + nbf, wv, lane);
      stage64(vtb + (size_t)(s+1)*64,        512, Vs + nbf, wv, lane);
    }

    f32x4 pacc[4];
    #pragma unroll
    for (int tt = 0; tt < 4; tt++){
      bf16x8 a0 = *(const bf16x8*)&Ks[buf + (tt*16 + cr)*64 + slot0];
      bf16x8 a1 = *(const bf16x8*)&Ks[buf + (tt*16 + cr)*64 + slot1];
      f32x4 z = {0.f, 0.f, 0.f, 0.f};
      z = MFMA(a0, qB[0], z);
      z = MFMA(a1, qB[1], z);
      pacc[tt] = z;
    }

    const u32 w0 = mw[2*s], w1 = mw[2*s+1];
    f32x4 vmx = {-3e38f, -3e38f, -3e38f, -3e38f};
    #pragma unroll
    for (int tt = 0; tt < 4; tt++){
      u32 nib = (((tt < 2) ? w0 : w1) >> (16*(tt & 1) + cg4)) & 0xFu;
      #pragma unroll
      for (int j = 0; j < 4; j++){
        float v = pacc[tt][j] * 0.125f + (((nib >> j) & 1u) ? 0.f : -10000.f);
        pacc[tt][j] = v;
        vmx[j] = fmaxf(vmx[j], v);
      }
    }
    float tm = fmaxf(fmaxf(vmx[0], vmx[1]), fmaxf(vmx[2], vmx[3]));
    tm = fmaxf(tm, __shfl_xor(tm, 16, 64));
    tm = fmaxf(tm, __shfl_xor(tm, 32, 64));

    float mnew = fmaxf(m, tm);
    float alpha = __expf(m - mnew);
    m = mnew;
    #pragma unroll
    for (int db = 0; db < 4; db++) oacc[db] *= alpha;

    f32x4 vsum = {0.f, 0.f, 0.f, 0.f};
    #pragma unroll
    for (int tt = 0; tt < 4; tt++){
      #pragma unroll
      for (int j = 0; j < 4; j++){
        float e = __expf(pacc[tt][j] - m);
        pacc[tt][j] = e;
        vsum[j] += e;
      }
    }
    vs = vs * alpha + (vsum[0] + vsum[1] + vsum[2] + vsum[3]);

    bf16x8 pa[2];
    #pragma unroll
    for (int c = 0; c < 2; c++)
      #pragma unroll
      for (int e = 0; e < 4; e++){
        pa[c][e]   = (__bf16)pacc[2*c][e];
        pa[c][4+e] = (__bf16)pacc[2*c+1][e];
      }

    #pragma unroll
    for (int c = 0; c < 2; c++){
      const int ch0 = ((4*c     + (cg >> 1)) ^ r7);
      const int ch1 = ((4*c + 2 + (cg >> 1)) ^ r7);
      const int sub = (cg & 1) << 3;
      #pragma unroll
      for (int db = 0; db < 4; db++){
        const char* vrow = (const char*)&Vs[buf + (db*16 + cr)*64];
        bf16x8 vb;
        ((uint2*)&vb)[0] = *(const uint2*)(vrow + (ch0 << 4) + sub);
        ((uint2*)&vb)[1] = *(const uint2*)(vrow + (ch1 << 4) + sub);
        oacc[db] = MFMA(pa[c], vb, oacc[db]);
      }
    }

    if (s + 1 < 8) { asm volatile("s_waitcnt vmcnt(0)" ::: "memory"); }
    __builtin_amdgcn_sched_barrier(0);
    BAR();
  }

  vs += __shfl_xor(vs, 16, 64);
  vs += __shfl_xor(vs, 32, 64);
  #pragma unroll
  for (int j = 0; j < 4; j++){
    float ds = __shfl(vs, cg4 + j, 64);
    float inv = 1.0f / ds;
    #pragma unroll
    for (int db = 0; db < 4; db++)
      ctx[((size_t)b * 512 + qw + cg4 + j) * 768 + hh*64 + 16*db + cr] = f2bf(oacc[db][j] * inv);
  }
}

// ---------------- head: K-split dense+tanh (grid = 12 col-chunks x 64 batches) ---------
__global__ __launch_bounds__(256)
void k_dense(const u16* __restrict__ hb, const float* __restrict__ W,
             const float* __restrict__ bias, float* __restrict__ xt){
  __shared__ float xs[768];
  __shared__ float red[256];
  const int b = blockIdx.y, t = threadIdx.x;
  const u16* hr = hb + (size_t)b * 512 * 768;   // row 0 of batch b
  xs[t] = bf2f(hr[t]); xs[t+256] = bf2f(hr[t+256]); xs[t+512] = bf2f(hr[t+512]);
  __syncthreads();
  const int col = blockIdx.x * 64 + (t & 63);
  const int ks  = t >> 6;                        // 0..3, k-slice of 192
  const float* Wp = W + (size_t)(ks * 192) * 768 + col;
  const float* xp = xs + ks * 192;
  float a = 0.f;
  #pragma unroll 8
  for (int k = 0; k < 192; k++) a += xp[k] * Wp[(size_t)k * 768];
  red[t] = a;
  __syncthreads();
  if (t < 64){
    float y = red[t] + red[t+64] + red[t+128] + red[t+192] + bias[col];
    xt[(size_t)b * 768 + col] = tanhf(y);
  }
}

__global__ void k_logits(const float* __restrict__ xt, const float* __restrict__ ow,
                         const float* __restrict__ ob, float* __restrict__ out){
  __shared__ float sb[4];
  int b = blockIdx.x, t = threadIdx.x;
  const float* x = xt + (size_t)b * 768;
  float s = x[t]*ow[t] + x[t+256]*ow[t+256] + x[t+512]*ow[t+512];
  for (int o = 32; o; o >>= 1) s += __shfl_down(s, o, 64);
  int wv = t >> 6, ln = t & 63;
  if (!ln) sb[wv] = s;
  __syncthreads();
  if (t == 0) out[b] = sb[0] + sb[1] + sb[2] + sb[3] + ob[0];
}

// ---------------- launch ----------------
extern "C" void kernel_launch(void* const* d_in, const int* in_sizes, int n_in,
                              void* d_out, int out_size, void* d_ws, size_t ws_size,
                              hipStream_t stream){
  if (n_in < 23) return;
  if (ws_size < 534000000ull) return;

  const int*   ids  = (const int*)  d_in[0];
  const int*   pos  = (const int*)  d_in[1];
  const void*  amsk =               d_in[2];
  const float* wemb = (const float*)d_in[3];
  const float* pemb = (const float*)d_in[4];
  const float* lng  = (const float*)d_in[5];
  const float* lnb  = (const float*)d_in[6];
  const float* Wqkv = (const float*)d_in[7];
  const float* bqkv = (const float*)d_in[8];
  const float* Wo   = (const float*)d_in[9];
  const float* bo   = (const float*)d_in[10];
  const float* ln1g = (const float*)d_in[11];
  const float* ln1b = (const float*)d_in[12];
  const float* W1   = (const float*)d_in[13];
  const float* b1   = (const float*)d_in[14];
  const float* W2   = (const float*)d_in[15];
  const float* b2   = (const float*)d_in[16];
  const float* ln2g = (const float*)d_in[17];
  const float* ln2b = (const float*)d_in[18];
  const float* dW   = (const float*)d_in[19];
  const float* db   = (const float*)d_in[20];
  const float* oW   = (const float*)d_in[21];
  const float* ob   = (const float*)d_in[22];

  char* ws = (char*)d_ws;
  u16*   hb   = (u16*)  (ws + 100663296);
  u16*   C    = (u16*)  (ws + 150994944);   // bf16 layer-output stream
  u16*   qkvp = (u16*)  (ws + 251658240);   // qp | kp (head-packed)
  u16*   vt   = (u16*)  (ws + 402653184);   // [bh][64][512]
  u16*   act  = (u16*)  (ws + 251658240);   // aliases qkvp+vt (disjoint lifetime)
  u16*   ctx  = (u16*)  (ws + 452984832);
  u32*   mbit = (u32*)  (ws + 503316480);
  u16*   wt   = (u16*)  (ws + 505413632);
  float* xt   = (float*)(ws + 533725184);
  int*   flag = (int*)  (ws + 533921792);

  u16* qp   = qkvp;
  u16* kp   = qkvp + (size_t)25165824;

  u16* WqkvT = wt;                                  // [l][2304][768]
  u16* WoT   = WqkvT + (size_t)2*2304*768;          // [l][768][768]
  u16* W1T   = WoT   + (size_t)2*768*768;           // [l][3072][768]
  u16* W2T   = W1T   + (size_t)2*3072*768;          // [l][768][3072]

  k_maskprobe<<<1, 256, 0, stream>>>((const unsigned char*)amsk, flag);
  k_maskbits<<<8192, 256, 0, stream>>>(amsk, flag, mbit);

  for (int l = 0; l < 2; l++){
    k_transpose<<<dim3(24, 72), 256, 0, stream>>>(Wqkv + (size_t)l*768*2304, WqkvT + (size_t)l*2304*768, 768, 2304);
    k_transpose<<<dim3(24, 24), 256, 0, stream>>>(Wo   + (size_t)l*768*768,  WoT   + (size_t)l*768*768,  768, 768);
    k_transpose<<<dim3(24, 96), 256, 0, stream>>>(W1   + (size_t)l*768*3072, W1T   + (size_t)l*3072*768, 768, 3072);
    k_transpose<<<dim3(96, 24), 256, 0, stream>>>(W2   + (size_t)l*3072*768, W2T   + (size_t)l*768*3072, 3072, 768);
  }

  k_embln<<<32768, 256, 0, stream>>>(ids, pos, mbit, wemb, pemb, lng, lnb, hb);

  for (int l = 0; l < 2; l++){
    k_gemm3<3><<<dim3(9, 256), 512, 0, stream>>>(hb, WqkvT + (size_t)l*2304*768, bqkv + l*2304, (void*)qkvp, (void*)vt, 32768, 2304, 768);
    k_attn3<<<dim3(8, 768), 256, 0, stream>>>(qp, kp, vt, mbit, ctx);
    k_gemm3<0><<<dim3(3, 256), 512, 0, stream>>>(ctx, WoT + (size_t)l*768*768, bo + l*768, (void*)C, nullptr, 32768, 768, 768);
    k_lnres<<<32768, 256, 0, stream>>>(C, ln1g + l*768, ln1b + l*768, hb);
    k_gemm3<2><<<dim3(12, 256), 512, 0, stream>>>(hb, W1T + (size_t)l*3072*768, b1 + l*3072, (void*)act, nullptr, 32768, 3072, 768);
    k_gemm3<0><<<dim3(3, 256), 512, 0, stream>>>(act, W2T + (size_t)l*768*3072, b2 + l*768, (void*)C, nullptr, 32768, 768, 3072);
    k_lnres<<<32768, 256, 0, stream>>>(C, ln2g + l*768, ln2b + l*768, hb);
  }

  k_dense<<<dim3(12, 64), 256, 0, stream>>>(hb, dW, db, xt);
  k_logits<<<64, 256, 0, stream>>>(xt, oW, ob, (float*)d_out);
}

// Round 15
// 1700.279 us; speedup vs baseline: 2.8147x; 2.8147x over previous
//
#include <hip/hip_runtime.h>

typedef unsigned short u16;
typedef unsigned int   u32;
typedef __bf16 bf16x8 __attribute__((ext_vector_type(8)));
typedef float  f32x4  __attribute__((ext_vector_type(4)));

#define DEVI __device__ __forceinline__

DEVI u16 f2bf(float f){
  u32 u = __builtin_bit_cast(u32, f);
  u32 r = (u + 0x7fffu + ((u >> 16) & 1u)) >> 16;   // RNE
  return (u16)r;
}
DEVI float bf2f(u16 u){
  u32 x = ((u32)u) << 16;
  return __builtin_bit_cast(float, x);
}

DEVI void gload16(const void* g, void* lds){
  __builtin_amdgcn_global_load_lds(
      (const __attribute__((address_space(1))) void*)g,
      (__attribute__((address_space(3))) void*)lds, 16, 0, 0);
}

DEVI f32x4 MFMA(bf16x8 a, bf16x8 b, f32x4 c){
  return __builtin_amdgcn_mfma_f32_16x16x32_bf16(a, b, c, 0, 0, 0);
}

#define BAR() do { asm volatile("s_barrier" ::: "memory"); \
                   __builtin_amdgcn_sched_barrier(0); } while(0)

// ---------------- mask dtype probe: 1 => uint8 bytes, 0 => int32 ----------------
__global__ void k_maskprobe(const unsigned char* __restrict__ m, int* __restrict__ flag){
  __shared__ int s;
  if (threadIdx.x == 0) s = 0;
  __syncthreads();
  int acc = 0;
  for (int i = threadIdx.x; i < 65536; i += 256)
    if ((i & 3) != 0 && m[i] != 0) acc++;
  atomicAdd(&s, acc);
  __syncthreads();
  if (threadIdx.x == 0) *flag = (s > 0) ? 1 : 0;
}

// ---------------- pack attn_mask to bitmask [B*S][16 words] ----------------
__global__ void k_maskbits(const void* __restrict__ mask, const int* __restrict__ flag,
                           u32* __restrict__ mb){
  int row  = blockIdx.x * 4 + (threadIdx.x >> 6);   // b*512+q
  int lane = threadIdx.x & 63;
  bool bytes = (*flag != 0);
  for (int c0 = 0; c0 < 512; c0 += 64){
    int v;
    if (bytes) v = ((const unsigned char*)mask)[(size_t)row * 512 + c0 + lane];
    else       v = ((const int*)mask)[(size_t)row * 512 + c0 + lane];
    unsigned long long bits = __ballot(v != 0);
    if (lane == 0){
      mb[(size_t)row * 16 + (c0 >> 5)]     = (u32)(bits & 0xffffffffull);
      mb[(size_t)row * 16 + (c0 >> 5) + 1] = (u32)(bits >> 32);
    }
  }
}

// ---------------- fused embed + node-average + LN0 -> bf16 hb ----------------
__global__ void k_embln(const int* __restrict__ ids, const int* __restrict__ pos,
                        const u32* __restrict__ mb, const float* __restrict__ wemb,
                        const float* __restrict__ pemb, const float* __restrict__ g,
                        const float* __restrict__ be, u16* __restrict__ hb){
  __shared__ float s1[4], s2[4];
  int row = blockIdx.x, t = threadIdx.x;
  int p = pos[row];
  float x0, x1, x2;
  if (p == 0){
    int b = row >> 9;
    const u32* mrow = mb + (size_t)row * 16;
    const int* pb = pos + ((size_t)b << 9);
    const int* ib = ids + ((size_t)b << 9);
    float a0 = 0.f, a1 = 0.f, a2 = 0.f, cnt = 0.f;
    #pragma unroll 8
    for (int k = 0; k < 512; k++){
      float w = (pb[k] >= 2 && ((mrow[k >> 5] >> (k & 31)) & 1)) ? 1.f : 0.f;
      const float* src = wemb + (size_t)ib[k] * 768;
      a0 += w * src[t]; a1 += w * src[t+256]; a2 += w * src[t+512];
      cnt += w;
    }
    float inv = 1.f / (cnt + 1e-10f);
    x0 = a0 * inv; x1 = a1 * inv; x2 = a2 * inv;
  } else {
    const float* src = wemb + (size_t)ids[row] * 768;
    x0 = src[t]; x1 = src[t+256]; x2 = src[t+512];
  }
  const float* pr = pemb + (size_t)p * 768;
  x0 += pr[t]; x1 += pr[t+256]; x2 += pr[t+512];
  float s = x0 + x1 + x2, q = x0*x0 + x1*x1 + x2*x2;
  for (int o = 32; o; o >>= 1){ s += __shfl_down(s, o, 64); q += __shfl_down(q, o, 64); }
  int wv = t >> 6, ln = t & 63;
  if (!ln){ s1[wv] = s; s2[wv] = q; }
  __syncthreads();
  s = s1[0]+s1[1]+s1[2]+s1[3]; q = s2[0]+s2[1]+s2[2]+s2[3];
  float mu = s * (1.f/768.f);
  float rs = rsqrtf(q * (1.f/768.f) - mu*mu + 1e-5f);
  u16* hbr = hb + (size_t)row * 768;
  hbr[t]     = f2bf((x0-mu)*rs*g[t]     + be[t]);
  hbr[t+256] = f2bf((x1-mu)*rs*g[t+256] + be[t+256]);
  hbr[t+512] = f2bf((x2-mu)*rs*g[t+512] + be[t+512]);
}

// lnres: hb (bf16, in-place) + C (bf16) -> LN -> hb
__global__ void k_lnres(const u16* __restrict__ C, const float* __restrict__ g,
                        const float* __restrict__ be, u16* __restrict__ hb){
  __shared__ float s1[4], s2[4];
  int row = blockIdx.x, t = threadIdx.x;
  u16* hr = hb + (size_t)row * 768;
  const u16* cr = C + (size_t)row * 768;
  float x0 = bf2f(hr[t])     + bf2f(cr[t]);
  float x1 = bf2f(hr[t+256]) + bf2f(cr[t+256]);
  float x2 = bf2f(hr[t+512]) + bf2f(cr[t+512]);
  float s = x0 + x1 + x2, q = x0*x0 + x1*x1 + x2*x2;
  for (int o = 32; o; o >>= 1){ s += __shfl_down(s, o, 64); q += __shfl_down(q, o, 64); }
  int wv = t >> 6, ln = t & 63;
  if (!ln){ s1[wv] = s; s2[wv] = q; }
  __syncthreads();
  s = s1[0]+s1[1]+s1[2]+s1[3]; q = s2[0]+s2[1]+s2[2]+s2[3];
  float mu = s * (1.f/768.f);
  float rs = rsqrtf(q * (1.f/768.f) - mu*mu + 1e-5f);
  hr[t]     = f2bf((x0-mu)*rs*g[t]     + be[t]);
  hr[t+256] = f2bf((x1-mu)*rs*g[t+256] + be[t+256]);
  hr[t+512] = f2bf((x2-mu)*rs*g[t+512] + be[t+512]);
}

// ---------------- weight transpose+cast: src[K][N] f32 -> dst[N][K] bf16 ----------------
__global__ void k_transpose(const float* __restrict__ src, u16* __restrict__ dst,
                            int K, int N){
  __shared__ float tile[32][33];
  int k0 = blockIdx.x * 32, n0 = blockIdx.y * 32;
  int tx = threadIdx.x & 31, ty = threadIdx.x >> 5;   // ty 0..7
  #pragma unroll
  for (int i = 0; i < 32; i += 8)
    tile[ty + i][tx] = src[(size_t)(k0 + ty + i) * N + n0 + tx];
  __syncthreads();
  #pragma unroll
  for (int i = 0; i < 32; i += 8)
    dst[(size_t)(n0 + ty + i) * K + k0 + tx] = f2bf(tile[tx][ty + i]);
}

// ========== 128x256 BK=32 GEMM, prefetch-distance-2 (A & B triple-buffered) ==========
// LDS 72 KiB: A 3x[128][32] (24 KB at u16 0/4096/8192) | B 3x[256][32] (48 KB at
// 12288 + 0/8192/16384). Rows = 4 chunks of 16B at slot = chunk ^ ((row>>1)&3).
// Per K-tile: read frags(t) -> stage A/B(t+2) -> MFMA -> vmcnt(3) -> barrier.
// bf16 epilogues (EPI 0/2/3) stage C in LDS and write full-line dwordx4 stores.

DEVI void stageA32(const u16* __restrict__ src, int K, u16* lds, int tid){
  int r = tid >> 2, c = tid & 3;
  int sc = c ^ ((r >> 1) & 3);
  gload16(src + (size_t)r*K + sc*8, lds + (size_t)tid*8);
}
DEVI void stageB32(const u16* __restrict__ src, int K, u16* lds, int tid){
  #pragma unroll
  for (int j = 0; j < 2; j++){
    int p = j*512 + tid;
    int r = p >> 2, c = p & 3;
    int sc = c ^ ((r >> 1) & 3);
    gload16(src + (size_t)r*K + sc*8, lds + (size_t)p*8);
  }
}

template<int EPI>
__global__ __launch_bounds__(512, 4)
void k_gemm3(const u16* __restrict__ A, const u16* __restrict__ BT,
             const float* __restrict__ bias, void* __restrict__ out,
             void* __restrict__ out2, int M, int N, int K){
  __shared__ __align__(16) u16 sm[36864];   // 72 KiB
  const int tid = threadIdx.x;
  const int w = tid >> 6, lane = tid & 63;
  const int wm = w >> 2, wn = w & 3;
  const int cr = lane & 15, cg = lane >> 4;

  // bijective XCD-chunked remap (m204)
  const int nbn = gridDim.x;
  const int nwg = nbn * gridDim.y;
  const int d   = blockIdx.y * nbn + blockIdx.x;
  const int xcd = d & 7, qq = nwg >> 3, rr = nwg & 7;
  const int logical = (xcd < rr ? xcd*(qq+1) : rr*(qq+1) + (xcd-rr)*qq) + (d >> 3);
  const int m0 = (logical / nbn) * 128;
  const int n0 = (logical % nbn) * 256;

  const int NT = K >> 5;
  const u16* Abase = A  + (size_t)m0 * K;
  const u16* Bbase = BT + (size_t)n0 * K;
  const int rowA = wm*64 + cr;
  const int rowB = wn*64 + cr;

  f32x4 acc[4][4] = {};
  bf16x8 afr[4], bfr[4];

  stageA32(Abase, K, sm, tid);
  stageB32(Bbase, K, sm + 12288, tid);
  if (NT > 1){
    stageA32(Abase + 32, K, sm + 4096, tid);
    stageB32(Bbase + 32, K, sm + 12288 + 8192, tid);
    asm volatile("s_waitcnt vmcnt(3)" ::: "memory");
  } else {
    asm volatile("s_waitcnt vmcnt(0)" ::: "memory");
  }
  __builtin_amdgcn_sched_barrier(0);
  BAR();

  int bcur = 0;
  for (int t = 0; t < NT; ++t){
    const int ab = bcur << 12;
    const int bb = 12288 + (bcur << 13);
    int bn2 = bcur + 2; if (bn2 >= 3) bn2 -= 3;

    #pragma unroll
    for (int n = 0; n < 4; n++){
      int r = rowB + n*16;
      bfr[n] = *(const bf16x8*)&sm[bb + r*32 + ((cg ^ ((r >> 1) & 3)) << 3)];
    }
    #pragma unroll
    for (int i = 0; i < 4; i++){
      int r = rowA + i*16;
      afr[i] = *(const bf16x8*)&sm[ab + r*32 + ((cg ^ ((r >> 1) & 3)) << 3)];
    }
    if (t + 2 < NT){
      stageA32(Abase + (size_t)(t+2)*32, K, sm + (bn2 << 12), tid);
      stageB32(Bbase + (size_t)(t+2)*32, K, sm + 12288 + (bn2 << 13), tid);
    }

    __builtin_amdgcn_s_setprio(1);
    #pragma unroll
    for (int i = 0; i < 4; i++)
      #pragma unroll
      for (int n = 0; n < 4; n++)
        acc[i][n] = MFMA(afr[i], bfr[n], acc[i][n]);
    __builtin_amdgcn_s_setprio(0);

    if (t + 2 < NT) { asm volatile("s_waitcnt vmcnt(3)" ::: "memory"); }
    else            { asm volatile("s_waitcnt vmcnt(0)" ::: "memory"); }
    __builtin_amdgcn_sched_barrier(0);
    BAR();
    bcur = bcur + 1; if (bcur >= 3) bcur = 0;
  }

  // ---- epilogue
  if (EPI == 1){
    #pragma unroll
    for (int n = 0; n < 4; n++){
      int col = n0 + wn*64 + n*16 + cr;
      float bv = bias[col];
      #pragma unroll
      for (int i = 0; i < 4; i++){
        #pragma unroll
        for (int j = 0; j < 4; j++){
          int row = m0 + wm*64 + i*16 + cg*4 + j;
          ((float*)out)[(size_t)row * N + col] = acc[i][n][j] + bv;
        }
      }
    }
  } else {
    const bool vblk = (EPI == 3) && (n0 >= 1536);
    const int LDC = vblk ? 266 : 264;
    #pragma unroll
    for (int n = 0; n < 4; n++){
      int coll = wn*64 + n*16 + cr;
      float bv = bias[n0 + coll];
      #pragma unroll
      for (int i = 0; i < 4; i++){
        #pragma unroll
        for (int j = 0; j < 4; j++){
          int rowl = wm*64 + i*16 + cg*4 + j;
          float v = acc[i][n][j] + bv;
          if (EPI == 2) v = 0.5f * v * (1.f + erff(v * 0.70710678118654752f));
          sm[rowl*LDC + coll] = f2bf(v);
        }
      }
    }
    BAR();
    if (EPI == 3){
      int b = m0 >> 9, s0 = m0 & 511;
      if (vblk){
        // direct transposed V write: vt[b*12+hd][d][s0..s0+127]
        int hd0 = (n0 - 1536) >> 6;
        int dl = lane >> 2, sc4 = lane & 3;
        #pragma unroll
        for (int it = 0; it < 8; it++){
          int gidx = it*8 + w;                 // 0..63
          int hh2 = gidx >> 4, dhi = (gidx >> 2) & 3, shi = gidx & 3;
          int dd2 = dhi*16 + dl;
          int schunk = shi*4 + sc4;
          u16 tmp[8];
          #pragma unroll
          for (int k = 0; k < 8; k++)
            tmp[k] = sm[(schunk*8 + k)*266 + hh2*64 + dd2];
          *(uint4*)((u16*)out2 + (((size_t)(b*12 + hd0 + hh2)*64 + dd2) << 9)
                    + s0 + schunk*8) = *(uint4*)tmp;
        }
      } else {
        // head-packed q/k scatter: 16B chunks, 128B contiguous per (s,head)
        #pragma unroll
        for (int it = 0; it < 8; it++){
          int idx = it*512 + tid;            // (s:128)(h:4)(c:8)
          int c = idx & 7, hh2 = (idx >> 3) & 3, s = idx >> 5;
          uint4 v4 = *(const uint4*)&sm[s*264 + hh2*64 + c*8];
          int col0 = n0 + hh2*64;
          int sec = (col0 >= 768) ? 1 : 0;
          int hd  = (col0 - sec*768) >> 6;
          *(uint4*)((u16*)out + (size_t)sec*25165824 +
                    (((size_t)(b*12 + hd)*512 + (m0 & 511) + s) << 6) + c*8) = v4;
        }
      }
    } else {
      #pragma unroll
      for (int it = 0; it < 8; it++){
        int idx = it*512 + tid;            // (r:128)(c8:32)
        int r = idx >> 5, c8 = idx & 31;
        uint4 v4 = *(const uint4*)&sm[r*264 + c8*8];
        *(uint4*)((u16*)out + (size_t)(m0 + r)*N + n0 + c8*8) = v4;
      }
    }
  }
}

// ---------------- attention v3: flash/online, swapped QK^T, LDS-staged K & V^T ----------
DEVI void stage64(const u16* __restrict__ src, int stride, u16* lds, int w, int lane){
  #pragma unroll
  for (int j = 0; j < 2; j++){
    int p  = j*256 + w*64 + lane;        // piece 0..511 (16B each)
    int r  = p >> 3;                     // row 0..63
    int c8 = (p & 7) ^ (r & 7);          // inverse-swizzled source chunk
    gload16(src + (size_t)r*stride + c8*8, lds + (size_t)p*8);
  }
}

__global__ __launch_bounds__(256, 4)
void k_attn3(const u16* __restrict__ qp, const u16* __restrict__ kp,
             const u16* __restrict__ vt, const u32* __restrict__ mb,
             u16* __restrict__ ctx){
  __shared__ __align__(16) u16 Ks[8192];   // 2 x [64][64]
  __shared__ __align__(16) u16 Vs[8192];   // 2 x [64 d][64 kv]
  const int tid = threadIdx.x, wv = tid >> 6, lane = tid & 63;
  const int cr = lane & 15, cg = lane >> 4;
  const int cg4 = cg * 4;
  const int r7 = cr & 7;

  const int dd = blockIdx.x + (blockIdx.y << 3);
  const int logical = (dd & 7) * 768 + (dd >> 3);
  const int bh = logical >> 3;
  const int qblk = logical & 7;
  const int b = bh / 12, hh = bh % 12;
  const int qw = qblk * 64 + wv * 16;
  const int qrow = qw + cr;
  const size_t base = (size_t)bh * 512 * 64;
  const u16* vtb = vt + (size_t)bh * 64 * 512;

  const int slot0 = ((cg    ) ^ r7) << 3;
  const int slot1 = ((4 + cg) ^ r7) << 3;

  bf16x8 qB[2];
  #pragma unroll
  for (int ks = 0; ks < 2; ks++)
    qB[ks] = *(const bf16x8*)&qp[base + (size_t)qrow * 64 + ks*32 + cg*8];

  u32 mw[16];
  {
    const u32* mrow = mb + ((size_t)b * 512 + qrow) * 16;
    #pragma unroll
    for (int i = 0; i < 4; i++){
      uint4 v4 = *(const uint4*)&mrow[i*4];
      mw[i*4+0] = v4.x; mw[i*4+1] = v4.y; mw[i*4+2] = v4.z; mw[i*4+3] = v4.w;
    }
  }

  stage64(kp + base, 64, Ks, wv, lane);
  stage64(vtb,      512, Vs, wv, lane);
  asm volatile("s_waitcnt vmcnt(0)" ::: "memory");
  __builtin_amdgcn_sched_barrier(0);
  BAR();

  float m = -3e38f, vs = 0.f;
  f32x4 oacc[4] = {};

  for (int s = 0; s < 8; ++s){
    const int buf = (s & 1) << 12;
    const int nbf = ((s + 1) & 1) << 12;

    if (s + 1 < 8){
      stage64(kp + base + (size_t)(s+1)*4096, 64, Ks + nbf, wv, lane);
      stage64(vtb + (size_t)(s+1)*64,        512, Vs + nbf, wv, lane);
    }

    f32x4 pacc[4];
    #pragma unroll
    for (int tt = 0; tt < 4; tt++){
      bf16x8 a0 = *(const bf16x8*)&Ks[buf + (tt*16 + cr)*64 + slot0];
      bf16x8 a1 = *(const bf16x8*)&Ks[buf + (tt*16 + cr)*64 + slot1];
      f32x4 z = {0.f, 0.f, 0.f, 0.f};
      z = MFMA(a0, qB[0], z);
      z = MFMA(a1, qB[1], z);
      pacc[tt] = z;
    }

    const u32 w0 = mw[2*s], w1 = mw[2*s+1];
    f32x4 vmx = {-3e38f, -3e38f, -3e38f, -3e38f};
    #pragma unroll
    for (int tt = 0; tt < 4; tt++){
      u32 nib = (((tt < 2) ? w0 : w1) >> (16*(tt & 1) + cg4)) & 0xFu;
      #pragma unroll
      for (int j = 0; j < 4; j++){
        float v = pacc[tt][j] * 0.125f + (((nib >> j) & 1u) ? 0.f : -10000.f);
        pacc[tt][j] = v;
        vmx[j] = fmaxf(vmx[j], v);
      }
    }
    float tm = fmaxf(fmaxf(vmx[0], vmx[1]), fmaxf(vmx[2], vmx[3]));
    tm = fmaxf(tm, __shfl_xor(tm, 16, 64));
    tm = fmaxf(tm, __shfl_xor(tm, 32, 64));

    float mnew = fmaxf(m, tm);
    float alpha = __expf(m - mnew);
    m = mnew;
    #pragma unroll
    for (int db = 0; db < 4; db++) oacc[db] *= alpha;

    f32x4 vsum = {0.f, 0.f, 0.f, 0.f};
    #pragma unroll
    for (int tt = 0; tt < 4; tt++){
      #pragma unroll
      for (int j = 0; j < 4; j++){
        float e = __expf(pacc[tt][j] - m);
        pacc[tt][j] = e;
        vsum[j] += e;
      }
    }
    vs = vs * alpha + (vsum[0] + vsum[1] + vsum[2] + vsum[3]);

    bf16x8 pa[2];
    #pragma unroll
    for (int c = 0; c < 2; c++)
      #pragma unroll
      for (int e = 0; e < 4; e++){
        pa[c][e]   = (__bf16)pacc[2*c][e];
        pa[c][4+e] = (__bf16)pacc[2*c+1][e];
      }

    #pragma unroll
    for (int c = 0; c < 2; c++){
      const int ch0 = ((4*c     + (cg >> 1)) ^ r7);
      const int ch1 = ((4*c + 2 + (cg >> 1)) ^ r7);
      const int sub = (cg & 1) << 3;
      #pragma unroll
      for (int db = 0; db < 4; db++){
        const char* vrow = (const char*)&Vs[buf + (db*16 + cr)*64];
        bf16x8 vb;
        ((uint2*)&vb)[0] = *(const uint2*)(vrow + (ch0 << 4) + sub);
        ((uint2*)&vb)[1] = *(const uint2*)(vrow + (ch1 << 4) + sub);
        oacc[db] = MFMA(pa[c], vb, oacc[db]);
      }
    }

    if (s + 1 < 8) { asm volatile("s_waitcnt vmcnt(0)" ::: "memory"); }
    __builtin_amdgcn_sched_barrier(0);
    BAR();
  }

  vs += __shfl_xor(vs, 16, 64);
  vs += __shfl_xor(vs, 32, 64);
  #pragma unroll
  for (int j = 0; j < 4; j++){
    float ds = __shfl(vs, cg4 + j, 64);
    float inv = 1.0f / ds;
    #pragma unroll
    for (int db = 0; db < 4; db++)
      ctx[((size_t)b * 512 + qw + cg4 + j) * 768 + hh*64 + 16*db + cr] = f2bf(oacc[db][j] * inv);
  }
}

// ---------------- head: K-split dense+tanh (grid = 12 col-chunks x 64 batches) ---------
__global__ __launch_bounds__(256)
void k_dense(const u16* __restrict__ hb, const float* __restrict__ W,
             const float* __restrict__ bias, float* __restrict__ xt){
  __shared__ float xs[768];
  __shared__ float red[256];
  const int b = blockIdx.y, t = threadIdx.x;
  const u16* hr = hb + (size_t)b * 512 * 768;   // row 0 of batch b
  xs[t] = bf2f(hr[t]); xs[t+256] = bf2f(hr[t+256]); xs[t+512] = bf2f(hr[t+512]);
  __syncthreads();
  const int col = blockIdx.x * 64 + (t & 63);
  const int ks  = t >> 6;                        // 0..3, k-slice of 192
  const float* Wp = W + (size_t)(ks * 192) * 768 + col;
  const float* xp = xs + ks * 192;
  float a = 0.f;
  #pragma unroll 8
  for (int k = 0; k < 192; k++) a += xp[k] * Wp[(size_t)k * 768];
  red[t] = a;
  __syncthreads();
  if (t < 64){
    float y = red[t] + red[t+64] + red[t+128] + red[t+192] + bias[col];
    xt[(size_t)b * 768 + col] = tanhf(y);
  }
}

__global__ void k_logits(const float* __restrict__ xt, const float* __restrict__ ow,
                         const float* __restrict__ ob, float* __restrict__ out){
  __shared__ float sb[4];
  int b = blockIdx.x, t = threadIdx.x;
  const float* x = xt + (size_t)b * 768;
  float s = x[t]*ow[t] + x[t+256]*ow[t+256] + x[t+512]*ow[t+512];
  for (int o = 32; o; o >>= 1) s += __shfl_down(s, o, 64);
  int wv = t >> 6, ln = t & 63;
  if (!ln) sb[wv] = s;
  __syncthreads();
  if (t == 0) out[b] = sb[0] + sb[1] + sb[2] + sb[3] + ob[0];
}

// ---------------- launch ----------------
extern "C" void kernel_launch(void* const* d_in, const int* in_sizes, int n_in,
                              void* d_out, int out_size, void* d_ws, size_t ws_size,
                              hipStream_t stream){
  if (n_in < 23) return;
  if (ws_size < 534000000ull) return;

  const int*   ids  = (const int*)  d_in[0];
  const int*   pos  = (const int*)  d_in[1];
  const void*  amsk =               d_in[2];
  const float* wemb = (const float*)d_in[3];
  const float* pemb = (const float*)d_in[4];
  const float* lng  = (const float*)d_in[5];
  const float* lnb  = (const float*)d_in[6];
  const float* Wqkv = (const float*)d_in[7];
  const float* bqkv = (const float*)d_in[8];
  const float* Wo   = (const float*)d_in[9];
  const float* bo   = (const float*)d_in[10];
  const float* ln1g = (const float*)d_in[11];
  const float* ln1b = (const float*)d_in[12];
  const float* W1   = (const float*)d_in[13];
  const float* b1   = (const float*)d_in[14];
  const float* W2   = (const float*)d_in[15];
  const float* b2   = (const float*)d_in[16];
  const float* ln2g = (const float*)d_in[17];
  const float* ln2b = (const float*)d_in[18];
  const float* dW   = (const float*)d_in[19];
  const float* db   = (const float*)d_in[20];
  const float* oW   = (const float*)d_in[21];
  const float* ob   = (const float*)d_in[22];

  char* ws = (char*)d_ws;
  u16*   hb   = (u16*)  (ws + 100663296);
  u16*   C    = (u16*)  (ws + 150994944);   // bf16 layer-output stream
  u16*   qkvp = (u16*)  (ws + 251658240);   // qp | kp (head-packed)
  u16*   vt   = (u16*)  (ws + 402653184);   // [bh][64][512]
  u16*   act  = (u16*)  (ws + 251658240);   // aliases qkvp+vt (disjoint lifetime)
  u16*   ctx  = (u16*)  (ws + 452984832);
  u32*   mbit = (u32*)  (ws + 503316480);
  u16*   wt   = (u16*)  (ws + 505413632);
  float* xt   = (float*)(ws + 533725184);
  int*   flag = (int*)  (ws + 533921792);

  u16* qp   = qkvp;
  u16* kp   = qkvp + (size_t)25165824;

  u16* WqkvT = wt;                                  // [l][2304][768]
  u16* WoT   = WqkvT + (size_t)2*2304*768;          // [l][768][768]
  u16* W1T   = WoT   + (size_t)2*768*768;           // [l][3072][768]
  u16* W2T   = W1T   + (size_t)2*3072*768;          // [l][768][3072]

  k_maskprobe<<<1, 256, 0, stream>>>((const unsigned char*)amsk, flag);
  k_maskbits<<<8192, 256, 0, stream>>>(amsk, flag, mbit);

  for (int l = 0; l < 2; l++){
    k_transpose<<<dim3(24, 72), 256, 0, stream>>>(Wqkv + (size_t)l*768*2304, WqkvT + (size_t)l*2304*768, 768, 2304);
    k_transpose<<<dim3(24, 24), 256, 0, stream>>>(Wo   + (size_t)l*768*768,  WoT   + (size_t)l*768*768,  768, 768);
    k_transpose<<<dim3(24, 96), 256, 0, stream>>>(W1   + (size_t)l*768*3072, W1T   + (size_t)l*3072*768, 768, 3072);
    k_transpose<<<dim3(96, 24), 256, 0, stream>>>(W2   + (size_t)l*3072*768, W2T   + (size_t)l*768*3072, 3072, 768);
  }

  k_embln<<<32768, 256, 0, stream>>>(ids, pos, mbit, wemb, pemb, lng, lnb, hb);

  for (int l = 0; l < 2; l++){
    k_gemm3<3><<<dim3(9, 256), 512, 0, stream>>>(hb, WqkvT + (size_t)l*2304*768, bqkv + l*2304, (void*)qkvp, (void*)vt, 32768, 2304, 768);
    k_attn3<<<dim3(8, 768), 256, 0, stream>>>(qp, kp, vt, mbit, ctx);
    k_gemm3<0><<<dim3(3, 256), 512, 0, stream>>>(ctx, WoT + (size_t)l*768*768, bo + l*768, (void*)C, nullptr, 32768, 768, 768);
    k_lnres<<<32768, 256, 0, stream>>>(C, ln1g + l*768, ln1b + l*768, hb);
    k_gemm3<2><<<dim3(12, 256), 512, 0, stream>>>(hb, W1T + (size_t)l*3072*768, b1 + l*3072, (void*)act, nullptr, 32768, 3072, 768);
    k_gemm3<0><<<dim3(3, 256), 512, 0, stream>>>(act, W2T + (size_t)l*768*3072, b2 + l*768, (void*)C, nullptr, 32768, 768, 3072);
    k_lnres<<<32768, 256, 0, stream>>>(C, ln2g + l*768, ln2b + l*768, hb);
  }

  k_dense<<<dim3(12, 64), 256, 0, stream>>>(hb, dW, db, xt);
  k_logits<<<64, 256, 0, stream>>>(xt, oW, ob, (float*)d_out);
}